// Round 1
// baseline (674.408 us; speedup 1.0000x reference)
//
#include <hip/hip_runtime.h>

#define N_NODES 100000
#define E_EDGES 800000
#define E_TOT   900000
#define F 512

typedef __attribute__((ext_vector_type(8))) short short8;
typedef __attribute__((ext_vector_type(4))) float f32x4;

__device__ __forceinline__ float bfu(unsigned int u) {
    union { unsigned int i; float f; } c; c.i = u << 16; return c.f;
}
__device__ __forceinline__ unsigned short f2b(float f) {
    union { float f; unsigned int u; } c; c.f = f;
    return (unsigned short)((c.u + 0x7fffu + ((c.u >> 16) & 1u)) >> 16);
}

// ---- CSR build ----
__global__ void k_init(unsigned int* deg, unsigned int* counter) {
    int i = blockIdx.x * 256 + threadIdx.x;
    if (i < N_NODES) deg[i] = 1u;           // self loop
    if (i == 0) *counter = 0u;
}

__global__ void k_hist(const int* __restrict__ ei, unsigned int* deg) {
    int e = blockIdx.x * 256 + threadIdx.x;
    if (e < E_EDGES) atomicAdd(&deg[ei[E_EDGES + e]], 1u);
}

__global__ void k_dis(const unsigned int* __restrict__ deg, float* __restrict__ dis) {
    int i = blockIdx.x * 256 + threadIdx.x;
    if (i < N_NODES) dis[i] = rsqrtf((float)deg[i]);
}

__global__ void k_alloc(const unsigned int* __restrict__ deg, unsigned int* counter,
                        int* __restrict__ rs, unsigned int* __restrict__ cursor) {
    int i = blockIdx.x * 256 + threadIdx.x;
    if (i < N_NODES) {
        unsigned int p = atomicAdd(counter, deg[i]);
        rs[i] = (int)p;
        cursor[i] = p;
    }
}

__global__ void k_scatter(const int* __restrict__ ei, const float* __restrict__ dis,
                          unsigned int* __restrict__ cursor,
                          int* __restrict__ col, float* __restrict__ val) {
    int e = blockIdx.x * 256 + threadIdx.x;
    if (e < E_TOT) {
        int s, d;
        if (e < E_EDGES) { s = ei[e]; d = ei[E_EDGES + e]; }
        else             { s = e - E_EDGES; d = s; }
        unsigned int p = atomicAdd(&cursor[d], 1u);
        col[p] = s;
        val[p] = dis[s] * dis[d];
    }
}

// ---- dtype converts ----
__global__ void k_cvtX(const float* __restrict__ xin, unsigned short* __restrict__ xb) {
    int i = blockIdx.x * 256 + threadIdx.x;   // exactly N*F/8 threads
    const float4* p = (const float4*)xin + (size_t)i * 2;
    float4 a = p[0], b = p[1];
    uint4 o;
    o.x = (unsigned)f2b(a.x) | ((unsigned)f2b(a.y) << 16);
    o.y = (unsigned)f2b(a.z) | ((unsigned)f2b(a.w) << 16);
    o.z = (unsigned)f2b(b.x) | ((unsigned)f2b(b.y) << 16);
    o.w = (unsigned)f2b(b.z) | ((unsigned)f2b(b.w) << 16);
    *(uint4*)(xb + (size_t)i * 8) = o;
}

__global__ void k_cvtW(const float* __restrict__ W, unsigned short* __restrict__ Wt) {
    int t = blockIdx.x * 256 + threadIdx.x;   // F*F threads
    if (t < F * F) {
        int n = t >> 9, k = t & 511;
        Wt[t] = f2b(W[k * F + n]);            // Wt[n][k] = W[k][n]
    }
}

// ---- GEMM: C[M,512] = A[M,512] x Bt[512,512]^T  (bf16 in, bf16 out, f32 acc) ----
__global__ __launch_bounds__(256)
void gemm_bt(const unsigned short* __restrict__ A, const unsigned short* __restrict__ Bt,
             unsigned short* __restrict__ C, int M) {
    __shared__ unsigned short lsa[128 * 72];
    __shared__ unsigned short lsb[128 * 72];
    int bx = blockIdx.x;        // M tile
    int by = blockIdx.y;        // N tile (0..3)
    int t  = threadIdx.x;
    int lane = t & 63, w = t >> 6;
    int wr = w >> 1, wc = w & 1;

    f32x4 acc[4][4];
    #pragma unroll
    for (int m = 0; m < 4; ++m)
        #pragma unroll
        for (int n = 0; n < 4; ++n)
            acc[m][n] = (f32x4){0.f, 0.f, 0.f, 0.f};

    int rowBase = bx * 128;

    for (int k0 = 0; k0 < F; k0 += 64) {
        #pragma unroll
        for (int i = 0; i < 4; ++i) {
            int c  = t + 256 * i;           // 0..1023
            int r  = c >> 3;                // 0..127
            int kc = (c & 7) * 8;           // 0..56
            int ga = rowBase + r; if (ga > M - 1) ga = M - 1;
            uint4 va = *(const uint4*)(A + (size_t)ga * F + k0 + kc);
            *(uint4*)&lsa[r * 72 + kc] = va;
            int gb = by * 128 + r;
            uint4 vb = *(const uint4*)(Bt + (size_t)gb * F + k0 + kc);
            *(uint4*)&lsb[r * 72 + kc] = vb;
        }
        __syncthreads();
        #pragma unroll
        for (int ks = 0; ks < 2; ++ks) {
            int koff = ks * 32 + (lane >> 4) * 8;
            short8 af[4], bfr[4];
            #pragma unroll
            for (int m = 0; m < 4; ++m)
                af[m] = *(short8*)&lsa[(wr * 64 + m * 16 + (lane & 15)) * 72 + koff];
            #pragma unroll
            for (int n = 0; n < 4; ++n)
                bfr[n] = *(short8*)&lsb[(wc * 64 + n * 16 + (lane & 15)) * 72 + koff];
            #pragma unroll
            for (int m = 0; m < 4; ++m)
                #pragma unroll
                for (int n = 0; n < 4; ++n)
                    acc[m][n] = __builtin_amdgcn_mfma_f32_16x16x32_bf16(af[m], bfr[n], acc[m][n], 0, 0, 0);
        }
        __syncthreads();
    }

    int rq = (lane >> 4) * 4, cq = lane & 15;
    #pragma unroll
    for (int m = 0; m < 4; ++m)
        #pragma unroll
        for (int n = 0; n < 4; ++n)
            #pragma unroll
            for (int j = 0; j < 4; ++j) {
                int row = rowBase + wr * 64 + m * 16 + rq + j;
                if (row < M) {
                    int colv = by * 128 + wc * 64 + n * 16 + cq;
                    C[(size_t)row * F + colv] = f2b(acc[m][n][j]);
                }
            }
}

// ---- aggregation: out[d] = sum_e val[e] * hin[col[e]] (+bias, opt relu) ----
__global__ __launch_bounds__(256)
void k_agg(const unsigned short* __restrict__ hin, const int* __restrict__ rs,
           const unsigned int* __restrict__ deg,
           const int* __restrict__ col, const float* __restrict__ val,
           const float* __restrict__ bias,
           unsigned short* __restrict__ outb, float* __restrict__ outf, int relu) {
    int node = blockIdx.x * 4 + (threadIdx.x >> 6);
    int lane = threadIdx.x & 63;
    if (node >= N_NODES) return;
    int e0 = rs[node], e1 = e0 + (int)deg[node];
    float acc[8] = {0, 0, 0, 0, 0, 0, 0, 0};
    for (int e = e0; e < e1; ++e) {
        int s = col[e];
        float wv = val[e];
        uint4 v = *(const uint4*)(hin + (size_t)s * F + lane * 8);
        acc[0] += wv * bfu(v.x & 0xffffu);
        acc[1] += wv * bfu(v.x >> 16);
        acc[2] += wv * bfu(v.y & 0xffffu);
        acc[3] += wv * bfu(v.y >> 16);
        acc[4] += wv * bfu(v.z & 0xffffu);
        acc[5] += wv * bfu(v.z >> 16);
        acc[6] += wv * bfu(v.w & 0xffffu);
        acc[7] += wv * bfu(v.w >> 16);
    }
    #pragma unroll
    for (int j = 0; j < 8; ++j) {
        acc[j] += bias[lane * 8 + j];
        if (relu) acc[j] = fmaxf(acc[j], 0.f);
    }
    if (outb) {
        uint4 o;
        o.x = (unsigned)f2b(acc[0]) | ((unsigned)f2b(acc[1]) << 16);
        o.y = (unsigned)f2b(acc[2]) | ((unsigned)f2b(acc[3]) << 16);
        o.z = (unsigned)f2b(acc[4]) | ((unsigned)f2b(acc[5]) << 16);
        o.w = (unsigned)f2b(acc[6]) | ((unsigned)f2b(acc[7]) << 16);
        *(uint4*)(outb + (size_t)node * F + lane * 8) = o;
    } else {
        float4 o1 = {acc[0], acc[1], acc[2], acc[3]};
        float4 o2 = {acc[4], acc[5], acc[6], acc[7]};
        *(float4*)(outf + (size_t)node * F + lane * 8) = o1;
        *(float4*)(outf + (size_t)node * F + lane * 8 + 4) = o2;
    }
}

extern "C" void kernel_launch(void* const* d_in, const int* in_sizes, int n_in,
                              void* d_out, int out_size, void* d_ws, size_t ws_size,
                              hipStream_t stream) {
    const float* x  = (const float*)d_in[0];
    const int*   ei = (const int*)d_in[1];
    const float* W1 = (const float*)d_in[2];
    const float* b1 = (const float*)d_in[3];
    const float* W2 = (const float*)d_in[4];
    const float* b2 = (const float*)d_in[5];
    float* out = (float*)d_out;

    char* ws = (char*)d_ws;
    size_t off = 0;
    auto alloc = [&](size_t bytes) -> void* {
        off = (off + 255) & ~(size_t)255;
        void* p = ws + off;
        off += bytes;
        return p;
    };

    unsigned short* tb  = (unsigned short*)alloc((size_t)N_NODES * F * 2); // GEMM out (bf16), reused for both layers
    unsigned short* W1t = (unsigned short*)alloc((size_t)F * F * 2);
    unsigned short* W2t = (unsigned short*)alloc((size_t)F * F * 2);
    unsigned int*   deg = (unsigned int*)alloc((size_t)N_NODES * 4);
    float*          dis = (float*)alloc((size_t)N_NODES * 4);
    int*            rs  = (int*)alloc((size_t)N_NODES * 4);
    unsigned int*   cur = (unsigned int*)alloc((size_t)N_NODES * 4);
    unsigned int*   cnt = (unsigned int*)alloc(256);
    int*            col = (int*)alloc((size_t)E_TOT * 4);
    float*          val = (float*)alloc((size_t)E_TOT * 4);

    // d_out doubles as scratch: lower half = h1 (bf16), upper half = x (bf16).
    unsigned short* h1b = (unsigned short*)d_out;
    unsigned short* xb  = (unsigned short*)((char*)d_out + (size_t)N_NODES * F * 2);

    int nb = (N_NODES + 255) / 256;

    k_init<<<nb, 256, 0, stream>>>(deg, cnt);
    k_hist<<<(E_EDGES + 255) / 256, 256, 0, stream>>>(ei, deg);
    k_dis<<<nb, 256, 0, stream>>>(deg, dis);
    k_alloc<<<nb, 256, 0, stream>>>(deg, cnt, rs, cur);
    k_scatter<<<(E_TOT + 255) / 256, 256, 0, stream>>>(ei, dis, cur, col, val);

    k_cvtW<<<(F * F + 255) / 256, 256, 0, stream>>>(W1, W1t);
    k_cvtW<<<(F * F + 255) / 256, 256, 0, stream>>>(W2, W2t);
    k_cvtX<<<(N_NODES * F / 8) / 256, 256, 0, stream>>>(x, xb);

    dim3 ggrid((N_NODES + 127) / 128, F / 128);

    // layer 1: h1 = relu(agg(x @ W1) + b1)
    gemm_bt<<<ggrid, 256, 0, stream>>>(xb, W1t, tb, N_NODES);
    k_agg<<<(N_NODES + 3) / 4, 256, 0, stream>>>(tb, rs, deg, col, val, b1, h1b, nullptr, 1);

    // layer 2: out = agg(h1 @ W2) + b2
    gemm_bt<<<ggrid, 256, 0, stream>>>(h1b, W2t, tb, N_NODES);
    k_agg<<<(N_NODES + 3) / 4, 256, 0, stream>>>(tb, rs, deg, col, val, b2, nullptr, out, 0);
}

// Round 3
// 673.384 us; speedup vs baseline: 1.0015x; 1.0015x over previous
//
#include <hip/hip_runtime.h>

#define N_NODES 100000
#define E_EDGES 800000
#define E_TOT   900000
#define F 512

typedef __attribute__((ext_vector_type(8))) short short8;
typedef __attribute__((ext_vector_type(4))) float f32x4;
typedef unsigned int u32;

__device__ __forceinline__ float bfu(unsigned int u) {
    union { unsigned int i; float f; } c; c.i = u << 16; return c.f;
}
__device__ __forceinline__ unsigned short f2b(float f) {
    union { float f; unsigned int u; } c; c.f = f;
    return (unsigned short)((c.u + 0x7fffu + ((c.u >> 16) & 1u)) >> 16);
}
__device__ __forceinline__ void gload_lds16(const void* g, void* l) {
    __builtin_amdgcn_global_load_lds(
        (const __attribute__((address_space(1))) u32*)g,
        (__attribute__((address_space(3))) u32*)l, 16, 0, 0);
}

// ---- CSR build ----
__global__ void k_init(unsigned int* deg, unsigned int* counter) {
    int i = blockIdx.x * 256 + threadIdx.x;
    if (i < N_NODES) deg[i] = 1u;           // self loop
    if (i == 0) *counter = 0u;
}

__global__ void k_hist(const int* __restrict__ ei, unsigned int* deg) {
    int e = blockIdx.x * 256 + threadIdx.x;
    if (e < E_EDGES) atomicAdd(&deg[ei[E_EDGES + e]], 1u);
}

__global__ void k_dis(const unsigned int* __restrict__ deg, float* __restrict__ dis) {
    int i = blockIdx.x * 256 + threadIdx.x;
    if (i < N_NODES) dis[i] = rsqrtf((float)deg[i]);
}

__global__ void k_alloc(const unsigned int* __restrict__ deg, unsigned int* counter,
                        int* __restrict__ rs, unsigned int* __restrict__ cursor) {
    int i = blockIdx.x * 256 + threadIdx.x;
    if (i < N_NODES) {
        unsigned int p = atomicAdd(counter, deg[i]);
        rs[i] = (int)p;
        cursor[i] = p;
    }
}

__global__ void k_scatter(const int* __restrict__ ei, const float* __restrict__ dis,
                          unsigned int* __restrict__ cursor,
                          int* __restrict__ col, float* __restrict__ val) {
    int e = blockIdx.x * 256 + threadIdx.x;
    if (e < E_TOT) {
        int s, d;
        if (e < E_EDGES) { s = ei[e]; d = ei[E_EDGES + e]; }
        else             { s = e - E_EDGES; d = s; }
        unsigned int p = atomicAdd(&cursor[d], 1u);
        col[p] = s;
        val[p] = dis[s] * dis[d];
    }
}

// ---- dtype converts ----
__global__ void k_cvtX(const float* __restrict__ xin, unsigned short* __restrict__ xb) {
    int i = blockIdx.x * 256 + threadIdx.x;   // exactly N*F/8 threads
    const float4* p = (const float4*)xin + (size_t)i * 2;
    float4 a = p[0], b = p[1];
    uint4 o;
    o.x = (unsigned)f2b(a.x) | ((unsigned)f2b(a.y) << 16);
    o.y = (unsigned)f2b(a.z) | ((unsigned)f2b(a.w) << 16);
    o.z = (unsigned)f2b(b.x) | ((unsigned)f2b(b.y) << 16);
    o.w = (unsigned)f2b(b.z) | ((unsigned)f2b(b.w) << 16);
    *(uint4*)(xb + (size_t)i * 8) = o;
}

__global__ void k_cvtW(const float* __restrict__ W, unsigned short* __restrict__ Wt) {
    int t = blockIdx.x * 256 + threadIdx.x;   // F*F threads
    if (t < F * F) {
        int n = t >> 9, k = t & 511;
        Wt[t] = f2b(W[k * F + n]);            // Wt[n][k] = W[k][n]
    }
}

// ---- GEMM (m97 structure): C[M,512] = A[M,512] x Bt[512,512]^T ----
// bf16 in, bf16 out, f32 acc. Linear LDS [128][64], global_load_lds width 16.
__global__ __launch_bounds__(256)
void gemm_bt(const unsigned short* __restrict__ A, const unsigned short* __restrict__ Bt,
             unsigned short* __restrict__ C, int M) {
    __shared__ unsigned short lsa[128 * 64];
    __shared__ unsigned short lsb[128 * 64];
    int bx = blockIdx.x;        // M tile
    int by = blockIdx.y;        // N tile (0..3)
    int t  = threadIdx.x;
    int lane = t & 63, w = t >> 6;
    int wr = w >> 1, wc = w & 1;

    f32x4 acc[4][4];
    #pragma unroll
    for (int m = 0; m < 4; ++m)
        #pragma unroll
        for (int n = 0; n < 4; ++n)
            acc[m][n] = (f32x4){0.f, 0.f, 0.f, 0.f};

    int rowBase = bx * 128;

    // per-thread staging coords: round i covers LDS bytes [(i*256+t)*16 ..]
    // row r = (i*256+t)>>3, short-offset kc = ((i*256+t)&7)*8
    int ar[4], akc[4], br[4];
    #pragma unroll
    for (int i = 0; i < 4; ++i) {
        int idx = i * 256 + t;
        int r = idx >> 3;
        akc[i] = (idx & 7) * 8;
        int ga = rowBase + r; if (ga >= M) ga = M - 1;
        ar[i] = ga;
        br[i] = by * 128 + r;
    }

    for (int k0 = 0; k0 < F; k0 += 64) {
        #pragma unroll
        for (int i = 0; i < 4; ++i) {
            int idx = i * 256 + t;
            gload_lds16(A + (size_t)ar[i] * F + k0 + akc[i], lsa + idx * 8);
            gload_lds16(Bt + (size_t)br[i] * F + k0 + akc[i], lsb + idx * 8);
        }
        __syncthreads();
        #pragma unroll
        for (int ks = 0; ks < 2; ++ks) {
            int koff = ks * 32 + (lane >> 4) * 8;
            short8 af[4], bfr[4];
            #pragma unroll
            for (int m = 0; m < 4; ++m)
                af[m] = *(short8*)&lsa[(wr * 64 + m * 16 + (lane & 15)) * 64 + koff];
            #pragma unroll
            for (int n = 0; n < 4; ++n)
                bfr[n] = *(short8*)&lsb[(wc * 64 + n * 16 + (lane & 15)) * 64 + koff];
            #pragma unroll
            for (int m = 0; m < 4; ++m)
                #pragma unroll
                for (int n = 0; n < 4; ++n)
                    acc[m][n] = __builtin_amdgcn_mfma_f32_16x16x32_bf16(af[m], bfr[n], acc[m][n], 0, 0, 0);
        }
        __syncthreads();
    }

    int rq = (lane >> 4) * 4, cq = lane & 15;
    #pragma unroll
    for (int m = 0; m < 4; ++m)
        #pragma unroll
        for (int n = 0; n < 4; ++n)
            #pragma unroll
            for (int j = 0; j < 4; ++j) {
                int row = rowBase + wr * 64 + m * 16 + rq + j;
                if (row < M) {
                    int colv = by * 128 + wc * 64 + n * 16 + cq;
                    C[(size_t)row * F + colv] = f2b(acc[m][n][j]);
                }
            }
}

// ---- aggregation: out[d] = sum_e val[e] * hin[col[e]] (+bias, opt relu) ----
__global__ __launch_bounds__(256)
void k_agg(const unsigned short* __restrict__ hin, const int* __restrict__ rs,
           const unsigned int* __restrict__ deg,
           const int* __restrict__ col, const float* __restrict__ val,
           const float* __restrict__ bias,
           unsigned short* __restrict__ outb, float* __restrict__ outf, int relu) {
    int node = blockIdx.x * 4 + (threadIdx.x >> 6);
    int lane = threadIdx.x & 63;
    if (node >= N_NODES) return;
    int e0 = rs[node], e1 = e0 + (int)deg[node];
    float acc[8] = {0, 0, 0, 0, 0, 0, 0, 0};
    for (int e = e0; e < e1; ++e) {
        int s = col[e];
        float wv = val[e];
        uint4 v = *(const uint4*)(hin + (size_t)s * F + lane * 8);
        acc[0] += wv * bfu(v.x & 0xffffu);
        acc[1] += wv * bfu(v.x >> 16);
        acc[2] += wv * bfu(v.y & 0xffffu);
        acc[3] += wv * bfu(v.y >> 16);
        acc[4] += wv * bfu(v.z & 0xffffu);
        acc[5] += wv * bfu(v.z >> 16);
        acc[6] += wv * bfu(v.w & 0xffffu);
        acc[7] += wv * bfu(v.w >> 16);
    }
    #pragma unroll
    for (int j = 0; j < 8; ++j) {
        acc[j] += bias[lane * 8 + j];
        if (relu) acc[j] = fmaxf(acc[j], 0.f);
    }
    if (outb) {
        uint4 o;
        o.x = (unsigned)f2b(acc[0]) | ((unsigned)f2b(acc[1]) << 16);
        o.y = (unsigned)f2b(acc[2]) | ((unsigned)f2b(acc[3]) << 16);
        o.z = (unsigned)f2b(acc[4]) | ((unsigned)f2b(acc[5]) << 16);
        o.w = (unsigned)f2b(acc[6]) | ((unsigned)f2b(acc[7]) << 16);
        *(uint4*)(outb + (size_t)node * F + lane * 8) = o;
    } else {
        // final fp32 output is never re-read: nontemporal store keeps the
        // gather working set (hin, 102 MB) resident in L3.
        f32x4 o1 = {acc[0], acc[1], acc[2], acc[3]};
        f32x4 o2 = {acc[4], acc[5], acc[6], acc[7]};
        f32x4* p = (f32x4*)(outf + (size_t)node * F + lane * 8);
        __builtin_nontemporal_store(o1, p);
        __builtin_nontemporal_store(o2, p + 1);
    }
}

extern "C" void kernel_launch(void* const* d_in, const int* in_sizes, int n_in,
                              void* d_out, int out_size, void* d_ws, size_t ws_size,
                              hipStream_t stream) {
    const float* x  = (const float*)d_in[0];
    const int*   ei = (const int*)d_in[1];
    const float* W1 = (const float*)d_in[2];
    const float* b1 = (const float*)d_in[3];
    const float* W2 = (const float*)d_in[4];
    const float* b2 = (const float*)d_in[5];
    float* out = (float*)d_out;

    char* ws = (char*)d_ws;
    size_t off = 0;
    auto alloc = [&](size_t bytes) -> void* {
        off = (off + 255) & ~(size_t)255;
        void* p = ws + off;
        off += bytes;
        return p;
    };

    unsigned short* tb  = (unsigned short*)alloc((size_t)N_NODES * F * 2); // GEMM out (bf16)
    unsigned short* W1t = (unsigned short*)alloc((size_t)F * F * 2);
    unsigned short* W2t = (unsigned short*)alloc((size_t)F * F * 2);
    unsigned int*   deg = (unsigned int*)alloc((size_t)N_NODES * 4);
    float*          dis = (float*)alloc((size_t)N_NODES * 4);
    int*            rs  = (int*)alloc((size_t)N_NODES * 4);
    unsigned int*   cur = (unsigned int*)alloc((size_t)N_NODES * 4);
    unsigned int*   cnt = (unsigned int*)alloc(256);
    int*            col = (int*)alloc((size_t)E_TOT * 4);
    float*          val = (float*)alloc((size_t)E_TOT * 4);

    // d_out doubles as scratch: lower half = h1 (bf16), upper half = x (bf16).
    unsigned short* h1b = (unsigned short*)d_out;
    unsigned short* xb  = (unsigned short*)((char*)d_out + (size_t)N_NODES * F * 2);

    int nb = (N_NODES + 255) / 256;

    k_init<<<nb, 256, 0, stream>>>(deg, cnt);
    k_hist<<<(E_EDGES + 255) / 256, 256, 0, stream>>>(ei, deg);
    k_dis<<<nb, 256, 0, stream>>>(deg, dis);
    k_alloc<<<nb, 256, 0, stream>>>(deg, cnt, rs, cur);
    k_scatter<<<(E_TOT + 255) / 256, 256, 0, stream>>>(ei, dis, cur, col, val);

    k_cvtW<<<(F * F + 255) / 256, 256, 0, stream>>>(W1, W1t);
    k_cvtW<<<(F * F + 255) / 256, 256, 0, stream>>>(W2, W2t);
    k_cvtX<<<(N_NODES * F / 8) / 256, 256, 0, stream>>>(x, xb);

    dim3 ggrid((N_NODES + 127) / 128, F / 128);

    // layer 1: h1 = relu(agg(x @ W1) + b1)
    gemm_bt<<<ggrid, 256, 0, stream>>>(xb, W1t, tb, N_NODES);
    k_agg<<<(N_NODES + 3) / 4, 256, 0, stream>>>(tb, rs, deg, col, val, b1, h1b, nullptr, 1);

    // layer 2: out = agg(h1 @ W2) + b2
    gemm_bt<<<ggrid, 256, 0, stream>>>(h1b, W2t, tb, N_NODES);
    k_agg<<<(N_NODES + 3) / 4, 256, 0, stream>>>(tb, rs, deg, col, val, b2, nullptr, out, 0);
}